// Round 6
// baseline (51.141 us; speedup 1.0000x reference)
//
#include <hip/hip_runtime.h>
#include <hip/hip_fp16.h>

// O = U X U^H, U = kron of 11 single-qubit SU(2) gates (2048^2 complex64).
// Reordered as O = U * (X * U^H):
//   K1 rowpassK1: Y = X U^H (butterflies over col index j, conj gates).
//      2 rows x 2048 cols per block (256 thr), 3 register phases (bits
//      7-10 | 3-6 | 0-2), float2 LDS plane w/ XOR swizzle j^((j>>5)&31)
//      -> all phases at the b64 bank floor. Y fp16.
//   K2 collowK2: column bits 0-6 (qubits 10..4), 128x32 tiles, 2 phases,
//      float2 LDS [r*32+c] (bank floor). Z fp16.
//   K3 colhighK3: column bits 7-10 (qubits 3..0), registers only,
//      rows at stride 128, writes Re(O) fp32.
// All global accesses 128-256 B per wave instruction. ~96 MB traffic.
// Round-5 post-mortem: latency-bound at 16 waves/CU; this round halves DS
// instr count (b64 vs split-plane b32) and doubles independent blocks/CU.

#define DIM 2048
#define NQ 11

__device__ __forceinline__ int swz(int j) { return j ^ ((j >> 5) & 31); }

__device__ __forceinline__ float2 cmul(float2 a, float2 b) {
    return make_float2(a.x * b.x - a.y * b.y, a.x * b.y + a.y * b.x);
}

// Composite gate g = Rz @ Ry @ Rx for qubit q; conj!=0 -> conjugate entries.
__device__ __forceinline__ void make_gate(const float* __restrict__ w, int q,
                                          int conj, float2* out4) {
    const float WM = 0.632455532033675866f;  // sqrt(2/5)
    float hx = 0.5f * WM * w[q * 3 + 0];
    float hy = 0.5f * WM * w[q * 3 + 1];
    float hz = 0.5f * WM * w[q * 3 + 2];
    float cx, sx, cy, sy, cz, sz;
    sincosf(hx, &sx, &cx);
    sincosf(hy, &sy, &cy);
    sincosf(hz, &sz, &cz);
    float2 m00 = make_float2(cy * cx,  sy * sx);
    float2 m01 = make_float2(-sy * cx, -cy * sx);
    float2 m10 = make_float2(sy * cx,  -cy * sx);
    float2 m11 = make_float2(cy * cx,  -sy * sx);
    float2 ez  = make_float2(cz, -sz);
    float2 ezc = make_float2(cz,  sz);
    float2 g00 = cmul(ez, m00);
    float2 g01 = cmul(ez, m01);
    float2 g10 = cmul(ezc, m10);
    float2 g11 = cmul(ezc, m11);
    float sgn = conj ? -1.f : 1.f;
    out4[0] = make_float2(g00.x, sgn * g00.y);
    out4[1] = make_float2(g01.x, sgn * g01.y);
    out4[2] = make_float2(g10.x, sgn * g10.y);
    out4[3] = make_float2(g11.x, sgn * g11.y);
}

__device__ __forceinline__ void bfly(float2& A, float2& B, const float2* g) {
    float2 a = A, b = B;
    A = make_float2(g[0].x * a.x - g[0].y * a.y + g[1].x * b.x - g[1].y * b.y,
                    g[0].x * a.y + g[0].y * a.x + g[1].x * b.y + g[1].y * b.x);
    B = make_float2(g[2].x * a.x - g[2].y * a.y + g[3].x * b.x - g[3].y * b.y,
                    g[2].x * a.y + g[2].y * a.x + g[3].x * b.y + g[3].y * b.x);
}

template <int ST>
__device__ __forceinline__ void stage16(float2* v, const float2* g) {
#pragma unroll
    for (int m = 0; m < 16; ++m)
        if (!(m & ST)) bfly(v[m], v[m + ST], g);
}

__device__ __forceinline__ void load_gate(const float2 (*gsh)[4], int q,
                                          float2* g) {
    g[0] = gsh[q][0]; g[1] = gsh[q][1]; g[2] = gsh[q][2]; g[3] = gsh[q][3];
}

__device__ __forceinline__ unsigned pack_h2(float2 v) {
    __half2 h = __float22half2_rn(v);
    return *reinterpret_cast<unsigned*>(&h);
}
__device__ __forceinline__ float2 unpack_h2(unsigned u) {
    __half2 h = *reinterpret_cast<__half2*>(&u);
    return __half22float2(h);
}

// ---------------- K1: Y = X U^H (row transform, 2 rows/block) --------------
__global__ __launch_bounds__(256, 4) void rowpassK1(
    const float* __restrict__ X, unsigned* __restrict__ Y,
    const float* __restrict__ wt) {
    __shared__ float2 lds[2 * DIM];      // 32 KB, one plane per row
    __shared__ float2 gsh[NQ][4];
    int t = threadIdx.x;
    if (t < NQ) make_gate(wt, t, 1, &gsh[t][0]);  // conjugated gates
    __syncthreads();

    int u = t & 127, rv = t >> 7;        // u = j bits 0-6, rv = row-in-block
    int row = blockIdx.x * 2 + rv;
    const float* xrow = X + (size_t)row * DIM;
    float2* L = lds + rv * DIM;

    // Phase A: j = u + 128m (bits 7-10 -> qubits 3,2,1,0). X real.
    float xr[16];
#pragma unroll
    for (int m = 0; m < 16; ++m) xr[m] = xrow[u + (m << 7)];

    float2 v[16], g[4];
    load_gate(gsh, 3, g);                // j bit 7, real-input stage
#pragma unroll
    for (int m = 0; m < 16; m += 2) {
        float a = xr[m], b = xr[m + 1];
        v[m]     = make_float2(g[0].x * a + g[1].x * b, g[0].y * a + g[1].y * b);
        v[m + 1] = make_float2(g[2].x * a + g[3].x * b, g[2].y * a + g[3].y * b);
    }
    load_gate(gsh, 2, g); stage16<2>(v, g);   // bit 8
    load_gate(gsh, 1, g); stage16<4>(v, g);   // bit 9
    load_gate(gsh, 0, g); stage16<8>(v, g);   // bit 10

#pragma unroll
    for (int m = 0; m < 16; ++m) L[swz(u + (m << 7))] = v[m];
    __syncthreads();

    // Phase M: j = (u&7) + 8m + 128*(u>>3) (bits 3-6 -> qubits 7,6,5,4).
    int uLo = u & 7, uHi = u >> 3;
#pragma unroll
    for (int m = 0; m < 16; ++m)
        v[m] = L[swz(uLo + (m << 3) + (uHi << 7))];
    load_gate(gsh, 7, g); stage16<1>(v, g);
    load_gate(gsh, 6, g); stage16<2>(v, g);
    load_gate(gsh, 5, g); stage16<4>(v, g);
    load_gate(gsh, 4, g); stage16<8>(v, g);
#pragma unroll
    for (int m = 0; m < 16; ++m)
        L[swz(uLo + (m << 3) + (uHi << 7))] = v[m];
    __syncthreads();

    // Phase F: j = m + 16u (bits 0-2 -> qubits 10,9,8).
#pragma unroll
    for (int m = 0; m < 16; ++m) v[m] = L[swz(m + (u << 4))];
    load_gate(gsh, 10, g); stage16<1>(v, g);
    load_gate(gsh, 9, g);  stage16<2>(v, g);
    load_gate(gsh, 8, g);  stage16<4>(v, g);

    // Store fp16: thread holds 16 consecutive j = 16u..16u+15.
    unsigned* yp = Y + (size_t)row * DIM + (u << 4);
#pragma unroll
    for (int e = 0; e < 4; ++e) {
        uint4 pk;
        pk.x = pack_h2(v[4 * e + 0]);
        pk.y = pack_h2(v[4 * e + 1]);
        pk.z = pack_h2(v[4 * e + 2]);
        pk.w = pack_h2(v[4 * e + 3]);
        *reinterpret_cast<uint4*>(yp + 4 * e) = pk;
    }
}

// -------- K2: column transform over row bits 0-6 (qubits 10..4) ------------
// Tile: 128 rows x 32 cols. 256 threads, 16 elems each, 2 phases.
__global__ __launch_bounds__(256, 4) void collowK2(
    const unsigned* __restrict__ Y, unsigned* __restrict__ Z,
    const float* __restrict__ wt) {
    __shared__ float2 lds[128 * 32];     // 32 KB
    __shared__ float2 gsh[NQ][4];
    int t = threadIdx.x;
    if (t < NQ) make_gate(wt, t, 0, &gsh[t][0]);
    __syncthreads();

    int c = t & 31, rr = t >> 5;         // rr = d bits 0-2 (phase A)
    int r0 = (blockIdx.x >> 6) * 128;    // 16 row groups
    int c0 = (blockIdx.x & 63) * 32;     // 64 col groups

    // Phase A: d = rr + 8m (bits 3-6 -> qubits 7,6,5,4).
    float2 v[16], g[4];
#pragma unroll
    for (int m = 0; m < 16; ++m)
        v[m] = unpack_h2(Y[(size_t)(r0 + rr + (m << 3)) * DIM + c0 + c]);

    load_gate(gsh, 7, g); stage16<1>(v, g);
    load_gate(gsh, 6, g); stage16<2>(v, g);
    load_gate(gsh, 5, g); stage16<4>(v, g);
    load_gate(gsh, 4, g); stage16<8>(v, g);
#pragma unroll
    for (int m = 0; m < 16; ++m) lds[(rr + (m << 3)) * 32 + c] = v[m];
    __syncthreads();

    // Phase F: d = m + 16rr (bits 0-2 -> qubits 10,9,8).
#pragma unroll
    for (int m = 0; m < 16; ++m) v[m] = lds[(m + (rr << 4)) * 32 + c];
    load_gate(gsh, 10, g); stage16<1>(v, g);
    load_gate(gsh, 9, g);  stage16<2>(v, g);
    load_gate(gsh, 8, g);  stage16<4>(v, g);

#pragma unroll
    for (int m = 0; m < 16; ++m)
        Z[(size_t)(r0 + m + (rr << 4)) * DIM + c0 + c] = pack_h2(v[m]);
}

// -------- K3: column transform over row bits 7-10 (qubits 3..0) ------------
// No LDS: thread owns rows d + 128m for one column j. Writes Re(O) fp32.
__global__ __launch_bounds__(256, 4) void colhighK3(
    const unsigned* __restrict__ Z, float* __restrict__ Out,
    const float* __restrict__ wt, int writeComplex) {
    __shared__ float2 gsh[NQ][4];
    int t = threadIdx.x;
    if (t < NQ) make_gate(wt, t, 0, &gsh[t][0]);
    __syncthreads();

    int b = blockIdx.x;
    int j = (b & 31) * 64 + (t & 63);
    int d = (b >> 5) * 4 + (t >> 6);     // row bits 0-6

    float2 v[16], g[4];
#pragma unroll
    for (int m = 0; m < 16; ++m)
        v[m] = unpack_h2(Z[(size_t)(d + (m << 7)) * DIM + j]);

    load_gate(gsh, 3, g); stage16<1>(v, g);   // row bit 7
    load_gate(gsh, 2, g); stage16<2>(v, g);   // bit 8
    load_gate(gsh, 1, g); stage16<4>(v, g);   // bit 9
    load_gate(gsh, 0, g); stage16<8>(v, g);   // bit 10

    if (!writeComplex) {
#pragma unroll
        for (int m = 0; m < 16; ++m)
            Out[(size_t)(d + (m << 7)) * DIM + j] = v[m].x;
    } else {
        float2* o2 = (float2*)Out;
#pragma unroll
        for (int m = 0; m < 16; ++m)
            o2[(size_t)(d + (m << 7)) * DIM + j] = v[m];
    }
}

extern "C" void kernel_launch(void* const* d_in, const int* in_sizes, int n_in,
                              void* d_out, int out_size, void* d_ws,
                              size_t ws_size, hipStream_t stream) {
    const float* X = (const float*)d_in[0];
    const float* wt = (const float*)d_in[1];
    float* out = (float*)d_out;
    unsigned* Y = (unsigned*)d_ws;                                   // 16 MB
    unsigned* Z = (unsigned*)((char*)d_ws + (size_t)DIM * DIM * 4);  // 16 MB

    rowpassK1<<<DIM / 2, 256, 0, stream>>>(X, Y, wt);
    collowK2<<<16 * 64, 256, 0, stream>>>(Y, Z, wt);
    int wc = (out_size >= 2 * DIM * DIM) ? 1 : 0;
    colhighK3<<<32 * 32, 256, 0, stream>>>(Z, out, wt, wc);
}